// Round 17
// baseline (154.302 us; speedup 1.0000x reference)
//
#include <hip/hip_runtime.h>

// Shapes
#define NB   256      // batch
#define E0   300      // embedding
#define EP   304      // padded embedding
#define F_   512      // features
#define KP   1536     // padded K (5*304=1520 -> 48 ksubs of 32 / 12 ss of 128)
#define NKT  48
#define LQ_  64
#define LA_  256

typedef __attribute__((ext_vector_type(4))) float f32x4;
typedef __attribute__((ext_vector_type(8))) short short8;

#define XQ_ELEMS (NB * (LQ_ + 4) * EP)   // 5,292,032
#define XA_ELEMS (NB * (LA_ + 4) * EP)   // 20,234,240
#define WF_ELEMS (F_ * KP)               // 786,432 (16f-fragment-packed)
#define OUTQ_ELEMS ((size_t)NB * F_ * LQ_)
#define XROWS (NB * (LQ_ + 4) + NB * (LA_ + 4))   // 83,968
#define XPBLK 24928                      // XROWS*76/256 (exact)
#define WPBLK 3072                       // WF_ELEMS/256

__device__ __forceinline__ unsigned short f2bf(float x) {
    unsigned int u = __float_as_uint(x);
    u = u + 0x7fffu + ((u >> 16) & 1u);   // RNE
    return (unsigned short)(u >> 16);
}

// Fused prep: x-part (verified r6-r16) + W-fragment part (verified r5-r16).
__global__ void prep_all(const float* __restrict__ q, const float* __restrict__ a,
                         const float* __restrict__ W,
                         unsigned short* __restrict__ xq, unsigned short* __restrict__ xa,
                         unsigned short* __restrict__ wfr)
{
    const int bid = blockIdx.x;
    if (bid < XPBLK) {
        int idx = bid * 256 + threadIdx.x;
        int row = idx / 76;
        int col = idx - row * 76;
        const float* src;
        unsigned short* dst;
        bool valid;
        if (row < NB * (LQ_ + 4)) {
            int b = row / (LQ_ + 4), lp = row - b * (LQ_ + 4);
            dst = xq + (size_t)row * EP;
            valid = (lp >= 2 && lp < 2 + LQ_);
            src = q + ((size_t)b * LQ_ + (lp - 2)) * E0;
        } else {
            int r2 = row - NB * (LQ_ + 4);
            int b = r2 / (LA_ + 4), lp = r2 - b * (LA_ + 4);
            dst = xa + (size_t)r2 * EP;
            valid = (lp >= 2 && lp < 2 + LA_);
            src = a + ((size_t)b * LA_ + (lp - 2)) * E0;
        }
        unsigned long long pk = 0ull;
        if (valid && col < 75) {
            const float4 v = reinterpret_cast<const float4*>(src)[col];
            pk = (unsigned long long)f2bf(v.x)
               | ((unsigned long long)f2bf(v.y) << 16)
               | ((unsigned long long)f2bf(v.z) << 32)
               | ((unsigned long long)f2bf(v.w) << 48);
        }
        *reinterpret_cast<unsigned long long*>(dst + (size_t)col * 4) = pk;
    } else {
        int idx = (bid - XPBLK) * 256 + threadIdx.x;
        int j    = idx & 7;
        int lane = (idx >> 3) & 63;
        int chunk = idx >> 9;
        int kc = chunk % NKT;
        int tile16 = chunk / NKT;
        int f  = tile16 * 16 + (lane & 15);
        int kp = kc * 32 + (lane >> 4) * 8 + j;
        int jj = kp / EP;
        int e  = kp - jj * EP;
        float v = (kp < 5 * EP && e < E0) ? W[(size_t)(jj * E0 + e) * F_ + f] : 0.f;
        wfr[idx] = f2bf(v);
    }
}

// r17 = r16 (256f x 128l, 4 waves, acc[4][8], ring-2 64 KB, 2 blocks/CU,
// grid 1280, merged fences: 2/SS, 64 MFMA per fence region) + ANTI-PHASE
// STAGGER: blocks with odd ((bid>>8)^bid) parity sleep ~1216 cyc once after
// the prologue barrier.  Under round-robin dispatch co-resident pairs are
// (b, b+256) -> opposite parity -> their MFMA bursts interleave with each
// other's fence stalls instead of colliding on the SIMD matrix pipe.
// Ledger identical to r16 (passed): prologue vmcnt(0); steady F1 vmcnt(8)
// retires the 2 W4s from prev burst2, F2 vmcnt(0) drains ST8 (publication
// before the end-of-SS barrier) + burst1 W4s; ring-2 WAR via F2's lgkm(0)
// before the end barrier; tail SS11 F1/F2 vmcnt(0), W chain 2+44+2 = 48.
__global__ __launch_bounds__(256, 2) void qa_gemm(
    const unsigned short* __restrict__ xq,
    const unsigned short* __restrict__ xa,
    const unsigned short* __restrict__ wfr,
    const float* __restrict__ bias,
    float* __restrict__ out)
{
    __shared__ __align__(16) unsigned short lds[2 * 16384];   // 64 KB Z-ring

    const int bid = blockIdx.x;
    const int wg  = (bid & 7) * 160 + (bid >> 3);   // XCD swizzle, 1280 % 8 == 0
    const int stag = ((bid >> 8) ^ bid) & 1;        // co-resident pair parity

    const int ftBase = (wg & 1) * 256;
    const int lt     = wg >> 1;                     // 0..639, tile of 128 l-rows

    const unsigned short* xp;
    float* ob;
    int Mb, lsh, Lp;
    if (lt < 128) { Mb = lt * 128;         xp = xq; lsh = 6; Lp = LQ_ + 4; ob = out; }
    else          { Mb = (lt - 128) * 128; xp = xa; lsh = 8; Lp = LA_ + 4; ob = out + OUTQ_ELEMS; }
    const int Lv = 1 << lsh;

    const int tid  = threadIdx.x;
    const int lane = tid & 63;
    const int wid  = tid >> 6;      // wave = 64f slice; all share the 128l tile
    const int lq   = lane >> 4;
    const int lr   = lane & 15;
    const int s_c  = (lane & 3) ^ ((lane >> 3) & 3);
    const int sub  = lane >> 2;
    const int dzA  = wid * 1024;    // shorts: stage rows wid*32..+15
    const int dzB  = dzA + 512;     //          and +16..+31

    const int mr0 = Mb + wid * 32 + sub;
    const int mr1 = mr0 + 16;
    const unsigned short* gZ0 = xp + (size_t)((mr0 >> lsh) * Lp + (mr0 & (Lv - 1))) * EP + s_c * 8;
    const unsigned short* gZ1 = xp + (size_t)((mr1 >> lsh) * Lp + (mr1 & (Lv - 1))) * EP + s_c * 8;

    // ---- W fragment chains (verified layout); two sets, stride 2 kc per load
    const unsigned short* wpA0 = wfr + (size_t)((ftBase >> 4) + wid * 4 + 0) * NKT * 512 + lane * 8;
    const unsigned short* wpA1 = wfr + (size_t)((ftBase >> 4) + wid * 4 + 1) * NKT * 512 + lane * 8;
    const unsigned short* wpA2 = wfr + (size_t)((ftBase >> 4) + wid * 4 + 2) * NKT * 512 + lane * 8;
    const unsigned short* wpA3 = wfr + (size_t)((ftBase >> 4) + wid * 4 + 3) * NKT * 512 + lane * 8;
    const unsigned short* wpB0 = wpA0 + 512;
    const unsigned short* wpB1 = wpA1 + 512;
    const unsigned short* wpB2 = wpA2 + 512;
    const unsigned short* wpB3 = wpA3 + 512;

    // ---- Z fragment LDS offsets (bytes within a ksub blk; r8-verified family)
    const int cs = (lq ^ ((lr >> 1) & 3)) * 16;
    int zoff[8];
#pragma unroll
    for (int n = 0; n < 8; ++n) zoff[n] = (n * 16 + lr) * 64 + cs;

#define GLLDS(p, d) __builtin_amdgcn_global_load_lds(                               \
        (const __attribute__((address_space(1))) void*)(p),                         \
        (__attribute__((address_space(3))) void*)(d), 16, 0, 0)
#define ST8(T) do { const int rb = ((T) & 1) * 16384; const size_t ko = (size_t)(T) * 128; \
    _Pragma("unroll") for (int kb = 0; kb < 4; ++kb) {                              \
        GLLDS(gZ0 + ko + kb * 32, lds + rb + kb * 4096 + dzA);                      \
        GLLDS(gZ1 + ko + kb * 32, lds + rb + kb * 4096 + dzB); } } while (0)
#define WLOAD(dst, p) do {                                                           \
    asm volatile("global_load_dwordx4 %0, %1, off" : "=v"(dst) : "v"(p) : "memory"); \
    (p) += 1024; } while (0)
#define W4A do { WLOAD(wA[0], wpA0); WLOAD(wA[1], wpA1);                             \
                 WLOAD(wA[2], wpA2); WLOAD(wA[3], wpA3); } while (0)
#define W4B do { WLOAD(wB[0], wpB0); WLOAD(wB[1], wpB1);                             \
                 WLOAD(wB[2], wpB2); WLOAD(wB[3], wpB3); } while (0)
#define ZRD8(DST, BLK) do { _Pragma("unroll") for (int n = 0; n < 8; ++n)            \
    DST[n] = *(const short8*)(bbase + (BLK) * 8192 + zoff[n]); } while (0)
#define SB __builtin_amdgcn_sched_barrier(0)
#define FENCE(VM, LG) do {                                                           \
    asm volatile("s_waitcnt vmcnt(" #VM ") lgkmcnt(" #LG ")" ::: "memory"); SB; } while (0)
#define MFMA32K(WU, ZU) do { __builtin_amdgcn_s_setprio(1);                          \
    _Pragma("unroll") for (int mf = 0; mf < 4; ++mf)                                 \
    _Pragma("unroll") for (int nt = 0; nt < 8; ++nt)                                 \
        acc[mf][nt] = __builtin_amdgcn_mfma_f32_16x16x32_bf16(                       \
            WU[mf], ZU[nt], acc[mf][nt], 0, 0, 0);                                   \
    __builtin_amdgcn_s_setprio(0); SB; } while (0)

    f32x4 acc[4][8] = {};
    short8 zA[8], zB[8], wA[4], wB[4];

    // Prologue: wA(k0), wB(k1), stage ss0; drain; publish.
    W4A; W4B;
    ST8(0);
    asm volatile("s_waitcnt vmcnt(0)\n\ts_barrier" ::: "memory");

    // Anti-phase stagger: odd pair-parity blocks shift their steady-state
    // timeline by ~1216 cyc (half a fence-region period) so the co-resident
    // block's MFMA bursts land in this block's stall windows and vice versa.
    if (stag) { asm volatile("s_sleep 19" ::: "memory"); }

    for (int S = 0; S < 11; ++S) {
        ST8(S + 1);
        const char* bbase = (const char*)lds + (S & 1) * 32768;
        ZRD8(zA, 0); ZRD8(zB, 1);
        FENCE(8, 0);                        // retire W4A°,W4B°; ST8 in flight
        MFMA32K(wA, zA); W4A;
        MFMA32K(wB, zB); W4B;
        ZRD8(zA, 2); ZRD8(zB, 3);
        FENCE(0, 0);                        // drain ST8 (publish) + burst1 W4s
        MFMA32K(wA, zA); W4A;
        MFMA32K(wB, zB); W4B;
        asm volatile("s_barrier" ::: "memory");
    }
    {   // SS 11: no stage; burst1 loads k46/k47; burst2 loads nothing
        const char* bbase = (const char*)lds + 32768;
        ZRD8(zA, 0); ZRD8(zB, 1);
        FENCE(0, 0);
        MFMA32K(wA, zA); W4A;
        MFMA32K(wB, zB); W4B;
        ZRD8(zA, 2); ZRD8(zB, 3);
        FENCE(0, 0);
        MFMA32K(wA, zA);
        MFMA32K(wB, zB);
    }

#undef MFMA32K
#undef FENCE
#undef SB
#undef ZRD8
#undef W4A
#undef W4B
#undef WLOAD
#undef ST8
#undef GLLDS

    // ---- epilogue: D row = f = lq*4+reg, col = l = lr (verified r1-r16)
#pragma unroll
    for (int nt = 0; nt < 8; ++nt) {
        const int m = Mb + nt * 16 + lr;
        const int b = m >> lsh;
        const int l = m & (Lv - 1);
        float* orow = ob + ((size_t)b * F_ << lsh) + l;
#pragma unroll
        for (int mf = 0; mf < 4; ++mf) {
            const int f0 = ftBase + wid * 64 + mf * 16 + lq * 4;
            const f32x4 v = acc[mf][nt];
#pragma unroll
            for (int r = 0; r < 4; ++r)
                orow[(size_t)(f0 + r) << lsh] = v[r] + __ldg(&bias[f0 + r]);
        }
    }
}

extern "C" void kernel_launch(void* const* d_in, const int* in_sizes, int n_in,
                              void* d_out, int out_size, void* d_ws, size_t ws_size,
                              hipStream_t stream)
{
    const float* q    = (const float*)d_in[0];
    const float* a    = (const float*)d_in[1];
    const float* W    = (const float*)d_in[2];
    const float* bias = (const float*)d_in[3];
    float* out = (float*)d_out;

    unsigned short* xq  = (unsigned short*)d_ws;
    unsigned short* xa  = xq + XQ_ELEMS;
    unsigned short* wfr = xa + XA_ELEMS;
    // ws needed: (XQ+XA+WF)*2 = 52.6 MB.  xa K-pad tail reads overrun <=32 B
    // into wfr: in-bounds; the matching W fragments are zero -> don't-care.

    prep_all<<<XPBLK + WPBLK, 256, 0, stream>>>(q, a, W, xq, xa, wfr);
    qa_gemm<<<1280, 256, 0, stream>>>(xq, xa, wfr, bias, out);
}